// Round 1
// baseline (2474.447 us; speedup 1.0000x reference)
//
#include <hip/hip_runtime.h>
#include <math.h>

// GPT-2 block, fp32. B=8 T=1024 C=768 H=8 D=96. M = B*T = 8192.
// Pipeline:
//  1. ln1(x)            -> bufA
//  2. qkv = bufA@W_attn^T + b_attn          -> bufQ   [8192 x 2304]
//  3. attention(bufQ)   -> bufA             (flash, causal)
//  4. xmid = bufA@W_proj^T + b_proj + x     -> bufX
//  5. ln2(xmid)         -> bufA
//  6. h = gelu(bufA@W_fc^T + b_fc)          -> bufQ   [8192 x 3072]
//  7. out = bufQ@W_fc_proj^T + b_fc_proj + xmid -> d_out

#define MROWS 8192
#define CDIM  768
#define TSEQ  1024

// ---------------- LayerNorm: one block per row ----------------
__global__ __launch_bounds__(256) void ln_kernel(const float* __restrict__ x,
                                                 const float* __restrict__ g,
                                                 const float* __restrict__ bta,
                                                 float* __restrict__ out) {
    int row = blockIdx.x;
    int t = threadIdx.x;
    const float* xr = x + (size_t)row * CDIM;
    float v0 = xr[t], v1 = xr[t + 256], v2 = xr[t + 512];
    float s = v0 + v1 + v2;
    float q = v0 * v0 + v1 * v1 + v2 * v2;
#pragma unroll
    for (int o = 32; o; o >>= 1) {
        s += __shfl_xor(s, o);
        q += __shfl_xor(q, o);
    }
    __shared__ float ls[4], lq[4];
    int w = t >> 6, lane = t & 63;
    if (lane == 0) { ls[w] = s; lq[w] = q; }
    __syncthreads();
    s = ls[0] + ls[1] + ls[2] + ls[3];
    q = lq[0] + lq[1] + lq[2] + lq[3];
    float mean = s * (1.0f / CDIM);
    float var = fmaxf(q * (1.0f / CDIM) - mean * mean, 0.0f);
    float rstd = rsqrtf(var + 1e-5f);
    float* orow = out + (size_t)row * CDIM;
    orow[t]       = (v0 - mean) * rstd * g[t]       + bta[t];
    orow[t + 256] = (v1 - mean) * rstd * g[t + 256] + bta[t + 256];
    orow[t + 512] = (v2 - mean) * rstd * g[t + 512] + bta[t + 512];
}

// ---------------- GEMM: out[M,N] = A[M,K] @ W[N,K]^T + bias (+res)(+gelu) ----
// BM=BN=128, BK=32, 256 threads, 8x8 per thread, strided mapping
// (rows ty+16i, cols tx+16j) for conflict-free scalar LDS reads.
template <int EPI>  // 0: bias, 1: bias+residual, 2: bias+gelu
__global__ __launch_bounds__(256) void gemm_kernel(const float* __restrict__ A,
                                                   const float* __restrict__ W,
                                                   const float* __restrict__ bias,
                                                   const float* __restrict__ res,
                                                   float* __restrict__ out,
                                                   int M, int N, int K) {
    __shared__ float As[32][132];
    __shared__ float Bs[32][132];
    int t = threadIdx.x;
    int tx = t & 15, ty = t >> 4;
    int row0 = blockIdx.y * 128, col0 = blockIdx.x * 128;
    float acc[8][8] = {};

    for (int k0 = 0; k0 < K; k0 += 32) {
        __syncthreads();
#pragma unroll
        for (int p = 0; p < 4; ++p) {
            int fi = t + 256 * p;           // 0..1023 over float4 slots
            int r = fi >> 3, c4 = fi & 7;   // 128 rows x 8 float4-cols
            float4 av = *reinterpret_cast<const float4*>(&A[(size_t)(row0 + r) * K + k0 + c4 * 4]);
            As[c4 * 4 + 0][r] = av.x;
            As[c4 * 4 + 1][r] = av.y;
            As[c4 * 4 + 2][r] = av.z;
            As[c4 * 4 + 3][r] = av.w;
            float4 bv = *reinterpret_cast<const float4*>(&W[(size_t)(col0 + r) * K + k0 + c4 * 4]);
            Bs[c4 * 4 + 0][r] = bv.x;
            Bs[c4 * 4 + 1][r] = bv.y;
            Bs[c4 * 4 + 2][r] = bv.z;
            Bs[c4 * 4 + 3][r] = bv.w;
        }
        __syncthreads();
#pragma unroll
        for (int k = 0; k < 32; ++k) {
            float a[8], b[8];
#pragma unroll
            for (int i = 0; i < 8; ++i) a[i] = As[k][ty + 16 * i];
#pragma unroll
            for (int j = 0; j < 8; ++j) b[j] = Bs[k][tx + 16 * j];
#pragma unroll
            for (int i = 0; i < 8; ++i)
#pragma unroll
                for (int j = 0; j < 8; ++j) acc[i][j] += a[i] * b[j];
        }
    }

#pragma unroll
    for (int i = 0; i < 8; ++i) {
        int r = row0 + ty + 16 * i;
#pragma unroll
        for (int j = 0; j < 8; ++j) {
            int c = col0 + tx + 16 * j;
            float v = acc[i][j] + bias[c];
            if (EPI == 1) v += res[(size_t)r * N + c];
            if (EPI == 2) {
                float u = v;
                float inner = 0.7978845608028654f * (u + 0.044715f * u * u * u);
                v = 0.5f * u * (1.0f + tanhf(inner));
            }
            out[(size_t)r * N + c] = v;
        }
    }
}

// ---------------- Flash attention (fp32, causal) ----------------
// Grid: (qtile 0..15, b*8+h 0..63). Block 256 = 16x16 threads.
// BM=64 q-rows, BN=64 keys/tile. Static LDS kept < 64 KB:
//   Qs[64][96] + KVs[64][96] (K then V share the buffer) + Ps[64][33] (P halves).
__global__ __launch_bounds__(256) void attn_kernel(const float* __restrict__ qkv,
                                                   float* __restrict__ y) {
    const int qt = blockIdx.x;
    const int bh = blockIdx.y;
    const int b = bh >> 3, h = bh & 7;
    const int t = threadIdx.x, tx = t & 15, ty = t >> 4;

    __shared__ float Qs[64][96];
    __shared__ float KVs[64][96];
    __shared__ float Ps[64][33];

    const size_t base = (size_t)b * TSEQ * 2304 + h * 96;
    const int q0 = qt * 64;

    // load Q tile (64 rows x 96) : 1536 float4 / 256 threads
#pragma unroll
    for (int p = 0; p < 6; ++p) {
        int fi = t + 256 * p;
        int r = fi / 24, c4 = fi % 24;
        *reinterpret_cast<float4*>(&Qs[r][c4 * 4]) =
            *reinterpret_cast<const float4*>(&qkv[base + (size_t)(q0 + r) * 2304 + c4 * 4]);
    }

    float m_i[4], l_i[4], o[4][6];
#pragma unroll
    for (int i = 0; i < 4; ++i) {
        m_i[i] = -INFINITY;
        l_i[i] = 0.0f;
#pragma unroll
        for (int j = 0; j < 6; ++j) o[i][j] = 0.0f;
    }
    const float scale = 0.10206207261596577f;  // 1/sqrt(96)

    for (int kt = 0; kt <= qt; ++kt) {
        const int k0 = kt * 64;
        __syncthreads();  // prev-iter V/P reads done
        // load K tile into KVs
#pragma unroll
        for (int p = 0; p < 6; ++p) {
            int fi = t + 256 * p;
            int r = fi / 24, c4 = fi % 24;
            *reinterpret_cast<float4*>(&KVs[r][c4 * 4]) =
                *reinterpret_cast<const float4*>(&qkv[base + (size_t)(k0 + r) * 2304 + 768 + c4 * 4]);
        }
        __syncthreads();

        // S = Q K^T : 4x4 per thread, rows ty+16i, cols tx+16j
        float s[4][4] = {};
#pragma unroll
        for (int d0 = 0; d0 < 96; d0 += 4) {
            float4 qv[4], kv[4];
#pragma unroll
            for (int i = 0; i < 4; ++i)
                qv[i] = *reinterpret_cast<const float4*>(&Qs[ty + 16 * i][d0]);
#pragma unroll
            for (int j = 0; j < 4; ++j)
                kv[j] = *reinterpret_cast<const float4*>(&KVs[tx + 16 * j][d0]);
#pragma unroll
            for (int i = 0; i < 4; ++i)
#pragma unroll
                for (int j = 0; j < 4; ++j)
                    s[i][j] += qv[i].x * kv[j].x + qv[i].y * kv[j].y +
                               qv[i].z * kv[j].z + qv[i].w * kv[j].w;
        }

        const bool diag = (kt == qt);
#pragma unroll
        for (int i = 0; i < 4; ++i) {
            int r = ty + 16 * i;
#pragma unroll
            for (int j = 0; j < 4; ++j) {
                int c = tx + 16 * j;
                float v = s[i][j] * scale;
                if (diag && c > r) v = -INFINITY;
                s[i][j] = v;
            }
        }

        // online softmax update (row groups = 16 tx lanes, shuffle width 16)
#pragma unroll
        for (int i = 0; i < 4; ++i) {
            float mx = fmaxf(fmaxf(s[i][0], s[i][1]), fmaxf(s[i][2], s[i][3]));
#pragma unroll
            for (int o_ = 8; o_; o_ >>= 1) mx = fmaxf(mx, __shfl_xor(mx, o_, 16));
            float mnew = fmaxf(m_i[i], mx);
            float sf = expf(m_i[i] - mnew);  // -inf -> 0 on first tile
            float rs = 0.0f;
#pragma unroll
            for (int j = 0; j < 4; ++j) {
                float p = expf(s[i][j] - mnew);
                s[i][j] = p;
                rs += p;
            }
#pragma unroll
            for (int o_ = 8; o_; o_ >>= 1) rs += __shfl_xor(rs, o_, 16);
            l_i[i] = l_i[i] * sf + rs;
            m_i[i] = mnew;
#pragma unroll
            for (int j = 0; j < 6; ++j) o[i][j] *= sf;
        }

        __syncthreads();  // K reads done; safe to overwrite KVs with V
        // load V tile into KVs; write P half 0 (keys 0..31)
#pragma unroll
        for (int p = 0; p < 6; ++p) {
            int fi = t + 256 * p;
            int r = fi / 24, c4 = fi % 24;
            *reinterpret_cast<float4*>(&KVs[r][c4 * 4]) =
                *reinterpret_cast<const float4*>(&qkv[base + (size_t)(k0 + r) * 2304 + 1536 + c4 * 4]);
        }
#pragma unroll
        for (int i = 0; i < 4; ++i) {
            Ps[ty + 16 * i][tx]      = s[i][0];
            Ps[ty + 16 * i][tx + 16] = s[i][1];
        }
        __syncthreads();

        // PV half 0: k = 0..31
#pragma unroll 4
        for (int k = 0; k < 32; ++k) {
            float pr[4];
#pragma unroll
            for (int i = 0; i < 4; ++i) pr[i] = Ps[ty + 16 * i][k];
            float2 vv[3];
#pragma unroll
            for (int jj = 0; jj < 3; ++jj)
                vv[jj] = *reinterpret_cast<const float2*>(&KVs[k][tx * 6 + 2 * jj]);
#pragma unroll
            for (int i = 0; i < 4; ++i) {
                o[i][0] += pr[i] * vv[0].x;
                o[i][1] += pr[i] * vv[0].y;
                o[i][2] += pr[i] * vv[1].x;
                o[i][3] += pr[i] * vv[1].y;
                o[i][4] += pr[i] * vv[2].x;
                o[i][5] += pr[i] * vv[2].y;
            }
        }
        __syncthreads();
        // write P half 1 (keys 32..63)
#pragma unroll
        for (int i = 0; i < 4; ++i) {
            Ps[ty + 16 * i][tx]      = s[i][2];
            Ps[ty + 16 * i][tx + 16] = s[i][3];
        }
        __syncthreads();
        // PV half 1: k = 32..63
#pragma unroll 4
        for (int k = 0; k < 32; ++k) {
            float pr[4];
#pragma unroll
            for (int i = 0; i < 4; ++i) pr[i] = Ps[ty + 16 * i][k];
            float2 vv[3];
#pragma unroll
            for (int jj = 0; jj < 3; ++jj)
                vv[jj] = *reinterpret_cast<const float2*>(&KVs[32 + k][tx * 6 + 2 * jj]);
#pragma unroll
            for (int i = 0; i < 4; ++i) {
                o[i][0] += pr[i] * vv[0].x;
                o[i][1] += pr[i] * vv[0].y;
                o[i][2] += pr[i] * vv[1].x;
                o[i][3] += pr[i] * vv[1].y;
                o[i][4] += pr[i] * vv[2].x;
                o[i][5] += pr[i] * vv[2].y;
            }
        }
    }

    // normalize + store y[b, t, h*96 + c]
#pragma unroll
    for (int i = 0; i < 4; ++i) {
        int r = q0 + ty + 16 * i;
        float invl = 1.0f / l_i[i];
        size_t orow = ((size_t)b * TSEQ + r) * CDIM + h * 96 + tx * 6;
#pragma unroll
        for (int j = 0; j < 6; ++j) y[orow + j] = o[i][j] * invl;
    }
}

// ---------------- launch ----------------
extern "C" void kernel_launch(void* const* d_in, const int* in_sizes, int n_in,
                              void* d_out, int out_size, void* d_ws, size_t ws_size,
                              hipStream_t stream) {
    const float* x        = (const float*)d_in[0];
    const float* ln1_g    = (const float*)d_in[1];
    const float* ln1_b    = (const float*)d_in[2];
    const float* ln2_g    = (const float*)d_in[3];
    const float* ln2_b    = (const float*)d_in[4];
    const float* W_attn   = (const float*)d_in[5];
    const float* b_attn   = (const float*)d_in[6];
    const float* W_proj   = (const float*)d_in[7];
    const float* b_proj   = (const float*)d_in[8];
    const float* W_fc     = (const float*)d_in[9];
    const float* b_fc     = (const float*)d_in[10];
    const float* W_fcproj = (const float*)d_in[11];
    const float* b_fcproj = (const float*)d_in[12];
    float* out = (float*)d_out;

    float* bufA = (float*)d_ws;                   // M*C   (x1 / y / x2)
    float* bufQ = bufA + (size_t)MROWS * CDIM;    // M*3072 (qkv / h)
    float* bufX = bufQ + (size_t)MROWS * 3072;    // M*C   (xmid)

    dim3 blk(256);

    // 1. ln1
    ln_kernel<<<dim3(MROWS), blk, 0, stream>>>(x, ln1_g, ln1_b, bufA);
    // 2. qkv
    gemm_kernel<0><<<dim3(2304 / 128, MROWS / 128), blk, 0, stream>>>(
        bufA, W_attn, b_attn, nullptr, bufQ, MROWS, 2304, CDIM);
    // 3. attention
    attn_kernel<<<dim3(16, 64), blk, 0, stream>>>(bufQ, bufA);
    // 4. proj + residual
    gemm_kernel<1><<<dim3(CDIM / 128, MROWS / 128), blk, 0, stream>>>(
        bufA, W_proj, b_proj, x, bufX, MROWS, CDIM, CDIM);
    // 5. ln2
    ln_kernel<<<dim3(MROWS), blk, 0, stream>>>(bufX, ln2_g, ln2_b, bufA);
    // 6. fc + gelu
    gemm_kernel<2><<<dim3(3072 / 128, MROWS / 128), blk, 0, stream>>>(
        bufA, W_fc, b_fc, nullptr, bufQ, MROWS, 3072, CDIM);
    // 7. fc_proj + residual -> out
    gemm_kernel<1><<<dim3(CDIM / 128, MROWS / 128), blk, 0, stream>>>(
        bufQ, W_fcproj, b_fcproj, bufX, out, MROWS, CDIM, 3072);
}

// Round 2
// 1015.168 us; speedup vs baseline: 2.4375x; 2.4375x over previous
//
#include <hip/hip_runtime.h>
#include <math.h>

// GPT-2 block. B=8 T=1024 C=768 H=8 D=96. M = B*T = 8192.
// GEMMs in fp16 MFMA (fp32 accum), attention math fp32 (fp16 inputs),
// LN/epilogues fp32.
//
// Pipeline:
//  0. convert weights fp32->fp16 (4 kernels)
//  1. ln1(x)                  -> actsh (f16)            [M,768]
//  2. qkv = actsh@W_attn^T+b  -> qkvh (f16)             [M,2304]
//  3. attention(qkvh)         -> actsh (f16)
//  4. xmid = actsh@W_proj^T+b + x      -> d_out (f32)
//  5. ln2(d_out)              -> actsh (f16)
//  6. h = gelu(actsh@W_fc^T+b)-> hh (f16)               [M,3072]
//  7. out = hh@W_fcproj^T+b + xmid     -> d_out (f32)

#define MROWS 8192
#define CDIM  768
#define TSEQ  1024

typedef _Float16 f16x8 __attribute__((ext_vector_type(8)));
typedef _Float16 f16x4 __attribute__((ext_vector_type(4)));
typedef float f32x4 __attribute__((ext_vector_type(4)));

__device__ __forceinline__ void async_copy16(void* lds, const void* g) {
    __builtin_amdgcn_global_load_lds(
        (const __attribute__((address_space(1))) unsigned int*)g,
        (__attribute__((address_space(3))) unsigned int*)lds, 16, 0, 0);
}

// ---------------- fp32 -> fp16 convert (weights) ----------------
__global__ __launch_bounds__(256) void f2h_kernel(const float* __restrict__ in,
                                                  _Float16* __restrict__ out, int n4) {
    int i = blockIdx.x * blockDim.x + threadIdx.x;
    if (i < n4) {
        float4 v = reinterpret_cast<const float4*>(in)[i];
        f16x4 h;
        h[0] = (_Float16)v.x; h[1] = (_Float16)v.y;
        h[2] = (_Float16)v.z; h[3] = (_Float16)v.w;
        reinterpret_cast<f16x4*>(out)[i] = h;
    }
}

// ---------------- LayerNorm -> fp16 out ----------------
__global__ __launch_bounds__(256) void ln_kernel(const float* __restrict__ x,
                                                 const float* __restrict__ g,
                                                 const float* __restrict__ bta,
                                                 _Float16* __restrict__ out) {
    int row = blockIdx.x;
    int t = threadIdx.x;
    const float* xr = x + (size_t)row * CDIM;
    float v0 = xr[t], v1 = xr[t + 256], v2 = xr[t + 512];
    float s = v0 + v1 + v2;
    float q = v0 * v0 + v1 * v1 + v2 * v2;
#pragma unroll
    for (int o = 32; o; o >>= 1) {
        s += __shfl_xor(s, o);
        q += __shfl_xor(q, o);
    }
    __shared__ float ls[4], lq[4];
    int w = t >> 6, lane = t & 63;
    if (lane == 0) { ls[w] = s; lq[w] = q; }
    __syncthreads();
    s = ls[0] + ls[1] + ls[2] + ls[3];
    q = lq[0] + lq[1] + lq[2] + lq[3];
    float mean = s * (1.0f / CDIM);
    float var = fmaxf(q * (1.0f / CDIM) - mean * mean, 0.0f);
    float rstd = rsqrtf(var + 1e-5f);
    _Float16* orow = out + (size_t)row * CDIM;
    orow[t]       = (_Float16)((v0 - mean) * rstd * g[t]       + bta[t]);
    orow[t + 256] = (_Float16)((v1 - mean) * rstd * g[t + 256] + bta[t + 256]);
    orow[t + 512] = (_Float16)((v2 - mean) * rstd * g[t + 512] + bta[t + 512]);
}

// ---------------- fp16 MFMA GEMM ----------------
// out[M,N] = A[M,K] @ W[N,K]^T + bias (+res)(+gelu)
// BM=BN=128, BK=32, 256 threads = 4 waves (2x2), 4x4 16x16 frags per wave.
// m97 structure: linear LDS + global_load_lds(16), 2 barriers per K-step.
template <int EPI, typename OutT>  // EPI 0: bias, 1: bias+res, 2: bias+gelu
__global__ __launch_bounds__(256) void hgemm(const _Float16* __restrict__ A,
                                             const _Float16* __restrict__ W,
                                             const float* __restrict__ bias,
                                             const float* __restrict__ res,
                                             OutT* __restrict__ out,
                                             int M, int N, int K) {
    __shared__ _Float16 As[128 * 32];
    __shared__ _Float16 Bs[128 * 32];
    const int t = threadIdx.x;
    const int wid = t >> 6;
    const int l = t & 63;
    const int fr = l & 15;          // fragment row/col within 16
    const int fq = l >> 4;          // K-chunk selector (0..3)
    const int wr = wid >> 1, wc = wid & 1;
    const int row0 = blockIdx.y * 128, col0 = blockIdx.x * 128;

    const _Float16* ga = A + (size_t)row0 * K;
    const _Float16* gb = W + (size_t)col0 * K;

    f32x4 acc[4][4] = {};

    // per-thread staging geometry: chunk ci covers row ci>>2, cols (ci&3)*8
    const int r_st = t >> 2, c_st = (t & 3) * 8;

    for (int k0 = 0; k0 < K; k0 += 32) {
        __syncthreads();  // previous iter's ds_reads complete before overwrite
#pragma unroll
        for (int p = 0; p < 2; ++p) {
            // LDS dest is wave-uniform base + lane*16 (linear layout)
            char* la = (char*)As + wid * 1024 + p * 4096;
            char* lb = (char*)Bs + wid * 1024 + p * 4096;
            int r = r_st + p * 64;
            async_copy16(la, ga + (size_t)r * K + k0 + c_st);
            async_copy16(lb, gb + (size_t)r * K + k0 + c_st);
        }
        __syncthreads();  // compiler drains vmcnt(0) before barrier

        f16x8 af[4], bf[4];
#pragma unroll
        for (int m = 0; m < 4; ++m)
            af[m] = *reinterpret_cast<const f16x8*>(&As[(wr * 64 + m * 16 + fr) * 32 + fq * 8]);
#pragma unroll
        for (int n = 0; n < 4; ++n)
            bf[n] = *reinterpret_cast<const f16x8*>(&Bs[(wc * 64 + n * 16 + fr) * 32 + fq * 8]);
#pragma unroll
        for (int m = 0; m < 4; ++m)
#pragma unroll
            for (int n = 0; n < 4; ++n)
                acc[m][n] = __builtin_amdgcn_mfma_f32_16x16x32_f16(af[m], bf[n], acc[m][n], 0, 0, 0);
    }

    // epilogue: D row = fq*4 + j, col = fr (within each 16x16 frag)
#pragma unroll
    for (int m = 0; m < 4; ++m) {
#pragma unroll
        for (int j = 0; j < 4; ++j) {
            int r = row0 + wr * 64 + m * 16 + fq * 4 + j;
#pragma unroll
            for (int n = 0; n < 4; ++n) {
                int c = col0 + wc * 64 + n * 16 + fr;
                float v = acc[m][n][j] + bias[c];
                if (EPI == 1) v += res[(size_t)r * N + c];
                if (EPI == 2) {
                    float u = v;
                    float inner = 0.7978845608028654f * (u + 0.044715f * u * u * u);
                    v = 0.5f * u * (1.0f + tanhf(inner));
                }
                out[(size_t)r * N + c] = (OutT)v;
            }
        }
    }
}

// ---------------- Flash attention (fp32 math, fp16 qkv in, fp16 out) --------
__global__ __launch_bounds__(256) void attn_kernel(const _Float16* __restrict__ qkv,
                                                   _Float16* __restrict__ y) {
    const int qt = blockIdx.x;
    const int bh = blockIdx.y;
    const int b = bh >> 3, h = bh & 7;
    const int t = threadIdx.x, tx = t & 15, ty = t >> 4;

    __shared__ float Qs[64][96];
    __shared__ float KVs[64][96];
    __shared__ float Ps[64][33];

    const size_t base = (size_t)b * TSEQ * 2304 + h * 96;
    const int q0 = qt * 64;

    // load Q tile (64 x 96): 768 8-half chunks over 256 threads
#pragma unroll
    for (int p = 0; p < 3; ++p) {
        int fi = t + 256 * p;
        int r = fi / 12, c8 = (fi % 12) * 8;
        f16x8 hv = *reinterpret_cast<const f16x8*>(&qkv[base + (size_t)(q0 + r) * 2304 + c8]);
#pragma unroll
        for (int e = 0; e < 8; ++e) Qs[r][c8 + e] = (float)hv[e];
    }

    float m_i[4], l_i[4], o[4][6];
#pragma unroll
    for (int i = 0; i < 4; ++i) {
        m_i[i] = -INFINITY;
        l_i[i] = 0.0f;
#pragma unroll
        for (int j = 0; j < 6; ++j) o[i][j] = 0.0f;
    }
    const float scale = 0.10206207261596577f;  // 1/sqrt(96)

    for (int kt = 0; kt <= qt; ++kt) {
        const int k0 = kt * 64;
        __syncthreads();
        // K tile
#pragma unroll
        for (int p = 0; p < 3; ++p) {
            int fi = t + 256 * p;
            int r = fi / 12, c8 = (fi % 12) * 8;
            f16x8 hv = *reinterpret_cast<const f16x8*>(&qkv[base + (size_t)(k0 + r) * 2304 + 768 + c8]);
#pragma unroll
            for (int e = 0; e < 8; ++e) KVs[r][c8 + e] = (float)hv[e];
        }
        __syncthreads();

        float s[4][4] = {};
#pragma unroll
        for (int d0 = 0; d0 < 96; d0 += 4) {
            float4 qv[4], kv[4];
#pragma unroll
            for (int i = 0; i < 4; ++i)
                qv[i] = *reinterpret_cast<const float4*>(&Qs[ty + 16 * i][d0]);
#pragma unroll
            for (int j = 0; j < 4; ++j)
                kv[j] = *reinterpret_cast<const float4*>(&KVs[tx + 16 * j][d0]);
#pragma unroll
            for (int i = 0; i < 4; ++i)
#pragma unroll
                for (int j = 0; j < 4; ++j)
                    s[i][j] += qv[i].x * kv[j].x + qv[i].y * kv[j].y +
                               qv[i].z * kv[j].z + qv[i].w * kv[j].w;
        }

        const bool diag = (kt == qt);
#pragma unroll
        for (int i = 0; i < 4; ++i) {
            int r = ty + 16 * i;
#pragma unroll
            for (int j = 0; j < 4; ++j) {
                int c = tx + 16 * j;
                float v = s[i][j] * scale;
                if (diag && c > r) v = -INFINITY;
                s[i][j] = v;
            }
        }

#pragma unroll
        for (int i = 0; i < 4; ++i) {
            float mx = fmaxf(fmaxf(s[i][0], s[i][1]), fmaxf(s[i][2], s[i][3]));
#pragma unroll
            for (int o_ = 8; o_; o_ >>= 1) mx = fmaxf(mx, __shfl_xor(mx, o_, 16));
            float mnew = fmaxf(m_i[i], mx);
            float sf = expf(m_i[i] - mnew);
            float rs = 0.0f;
#pragma unroll
            for (int j = 0; j < 4; ++j) {
                float p = expf(s[i][j] - mnew);
                s[i][j] = p;
                rs += p;
            }
#pragma unroll
            for (int o_ = 8; o_; o_ >>= 1) rs += __shfl_xor(rs, o_, 16);
            l_i[i] = l_i[i] * sf + rs;
            m_i[i] = mnew;
#pragma unroll
            for (int j = 0; j < 6; ++j) o[i][j] *= sf;
        }

        __syncthreads();
        // V tile + P half 0
#pragma unroll
        for (int p = 0; p < 3; ++p) {
            int fi = t + 256 * p;
            int r = fi / 12, c8 = (fi % 12) * 8;
            f16x8 hv = *reinterpret_cast<const f16x8*>(&qkv[base + (size_t)(k0 + r) * 2304 + 1536 + c8]);
#pragma unroll
            for (int e = 0; e < 8; ++e) KVs[r][c8 + e] = (float)hv[e];
        }
#pragma unroll
        for (int i = 0; i < 4; ++i) {
            Ps[ty + 16 * i][tx]      = s[i][0];
            Ps[ty + 16 * i][tx + 16] = s[i][1];
        }
        __syncthreads();

#pragma unroll 4
        for (int k = 0; k < 32; ++k) {
            float pr[4];
#pragma unroll
            for (int i = 0; i < 4; ++i) pr[i] = Ps[ty + 16 * i][k];
            float2 vv[3];
#pragma unroll
            for (int jj = 0; jj < 3; ++jj)
                vv[jj] = *reinterpret_cast<const float2*>(&KVs[k][tx * 6 + 2 * jj]);
#pragma unroll
            for (int i = 0; i < 4; ++i) {
                o[i][0] += pr[i] * vv[0].x;
                o[i][1] += pr[i] * vv[0].y;
                o[i][2] += pr[i] * vv[1].x;
                o[i][3] += pr[i] * vv[1].y;
                o[i][4] += pr[i] * vv[2].x;
                o[i][5] += pr[i] * vv[2].y;
            }
        }
        __syncthreads();
#pragma unroll
        for (int i = 0; i < 4; ++i) {
            Ps[ty + 16 * i][tx]      = s[i][2];
            Ps[ty + 16 * i][tx + 16] = s[i][3];
        }
        __syncthreads();
#pragma unroll 4
        for (int k = 0; k < 32; ++k) {
            float pr[4];
#pragma unroll
            for (int i = 0; i < 4; ++i) pr[i] = Ps[ty + 16 * i][k];
            float2 vv[3];
#pragma unroll
            for (int jj = 0; jj < 3; ++jj)
                vv[jj] = *reinterpret_cast<const float2*>(&KVs[32 + k][tx * 6 + 2 * jj]);
#pragma unroll
            for (int i = 0; i < 4; ++i) {
                o[i][0] += pr[i] * vv[0].x;
                o[i][1] += pr[i] * vv[0].y;
                o[i][2] += pr[i] * vv[1].x;
                o[i][3] += pr[i] * vv[1].y;
                o[i][4] += pr[i] * vv[2].x;
                o[i][5] += pr[i] * vv[2].y;
            }
        }
    }

#pragma unroll
    for (int i = 0; i < 4; ++i) {
        int r = q0 + ty + 16 * i;
        float invl = 1.0f / l_i[i];
        _Float16* yrow = y + ((size_t)b * TSEQ + r) * CDIM + h * 96 + tx * 6;
#pragma unroll
        for (int j = 0; j < 6; ++j) yrow[j] = (_Float16)(o[i][j] * invl);
    }
}

// ---------------- launch ----------------
extern "C" void kernel_launch(void* const* d_in, const int* in_sizes, int n_in,
                              void* d_out, int out_size, void* d_ws, size_t ws_size,
                              hipStream_t stream) {
    const float* x        = (const float*)d_in[0];
    const float* ln1_g    = (const float*)d_in[1];
    const float* ln1_b    = (const float*)d_in[2];
    const float* ln2_g    = (const float*)d_in[3];
    const float* ln2_b    = (const float*)d_in[4];
    const float* W_attn   = (const float*)d_in[5];
    const float* b_attn   = (const float*)d_in[6];
    const float* W_proj   = (const float*)d_in[7];
    const float* b_proj   = (const float*)d_in[8];
    const float* W_fc     = (const float*)d_in[9];
    const float* b_fc     = (const float*)d_in[10];
    const float* W_fcproj = (const float*)d_in[11];
    const float* b_fcproj = (const float*)d_in[12];
    float* out = (float*)d_out;

    // fp16 workspace layout (halves)
    _Float16* qkvh  = (_Float16*)d_ws;                       // M*2304
    _Float16* actsh = qkvh + (size_t)MROWS * 2304;           // M*768 (x1/y/x2)
    _Float16* hh    = actsh + (size_t)MROWS * CDIM;          // M*3072
    _Float16* wah   = hh + (size_t)MROWS * 3072;             // 2304*768
    _Float16* wph   = wah + (size_t)2304 * 768;              // 768*768
    _Float16* wfh   = wph + (size_t)768 * 768;               // 3072*768
    _Float16* wfph  = wfh + (size_t)3072 * 768;              // 768*3072

    dim3 blk(256);

    // 0. weight converts
    f2h_kernel<<<dim3((2304 * 768 / 4 + 255) / 256), blk, 0, stream>>>(W_attn, wah, 2304 * 768 / 4);
    f2h_kernel<<<dim3((768 * 768 / 4 + 255) / 256), blk, 0, stream>>>(W_proj, wph, 768 * 768 / 4);
    f2h_kernel<<<dim3((3072 * 768 / 4 + 255) / 256), blk, 0, stream>>>(W_fc, wfh, 3072 * 768 / 4);
    f2h_kernel<<<dim3((768 * 3072 / 4 + 255) / 256), blk, 0, stream>>>(W_fcproj, wfph, 768 * 3072 / 4);

    // 1. ln1
    ln_kernel<<<dim3(MROWS), blk, 0, stream>>>(x, ln1_g, ln1_b, actsh);
    // 2. qkv (f16 out)
    hgemm<0, _Float16><<<dim3(2304 / 128, MROWS / 128), blk, 0, stream>>>(
        actsh, wah, b_attn, nullptr, qkvh, MROWS, 2304, CDIM);
    // 3. attention -> actsh (f16)
    attn_kernel<<<dim3(16, 64), blk, 0, stream>>>(qkvh, actsh);
    // 4. proj + residual -> d_out (fp32 xmid)
    hgemm<1, float><<<dim3(CDIM / 128, MROWS / 128), blk, 0, stream>>>(
        actsh, wph, b_proj, x, out, MROWS, CDIM, CDIM);
    // 5. ln2
    ln_kernel<<<dim3(MROWS), blk, 0, stream>>>(out, ln2_g, ln2_b, actsh);
    // 6. fc + gelu (f16 out)
    hgemm<2, _Float16><<<dim3(3072 / 128, MROWS / 128), blk, 0, stream>>>(
        actsh, wfh, b_fc, nullptr, hh, MROWS, 3072, CDIM);
    // 7. fc_proj + residual -> d_out
    hgemm<1, float><<<dim3(CDIM / 128, MROWS / 128), blk, 0, stream>>>(
        hh, wfph, b_fcproj, out, out, MROWS, CDIM, 3072);
}

// Round 4
// 425.207 us; speedup vs baseline: 5.8194x; 2.3875x over previous
//
#include <hip/hip_runtime.h>
#include <math.h>

// GPT-2 block. B=8 T=1024 C=768 H=8 D=96. M = B*T = 8192.
// GEMMs + attention in fp16 MFMA (fp32 accum/softmax), LN/epilogues fp32.

#define MROWS 8192
#define CDIM  768
#define TSEQ  1024

typedef _Float16 f16x8 __attribute__((ext_vector_type(8)));
typedef _Float16 f16x4 __attribute__((ext_vector_type(4)));
typedef float f32x4 __attribute__((ext_vector_type(4)));

__device__ __forceinline__ void async_copy16(void* lds, const void* g) {
    __builtin_amdgcn_global_load_lds(
        (const __attribute__((address_space(1))) unsigned int*)g,
        (__attribute__((address_space(3))) unsigned int*)lds, 16, 0, 0);
}

// ---------------- fp32 -> fp16 convert (weights) ----------------
__global__ __launch_bounds__(256) void f2h_kernel(const float* __restrict__ in,
                                                  _Float16* __restrict__ out, int n4) {
    int i = blockIdx.x * blockDim.x + threadIdx.x;
    if (i < n4) {
        float4 v = reinterpret_cast<const float4*>(in)[i];
        f16x4 h;
        h[0] = (_Float16)v.x; h[1] = (_Float16)v.y;
        h[2] = (_Float16)v.z; h[3] = (_Float16)v.w;
        reinterpret_cast<f16x4*>(out)[i] = h;
    }
}

// ---------------- LayerNorm -> fp16 out ----------------
__global__ __launch_bounds__(256) void ln_kernel(const float* __restrict__ x,
                                                 const float* __restrict__ g,
                                                 const float* __restrict__ bta,
                                                 _Float16* __restrict__ out) {
    int row = blockIdx.x;
    int t = threadIdx.x;
    const float* xr = x + (size_t)row * CDIM;
    float v0 = xr[t], v1 = xr[t + 256], v2 = xr[t + 512];
    float s = v0 + v1 + v2;
    float q = v0 * v0 + v1 * v1 + v2 * v2;
#pragma unroll
    for (int o = 32; o; o >>= 1) {
        s += __shfl_xor(s, o);
        q += __shfl_xor(q, o);
    }
    __shared__ float ls[4], lq[4];
    int w = t >> 6, lane = t & 63;
    if (lane == 0) { ls[w] = s; lq[w] = q; }
    __syncthreads();
    s = ls[0] + ls[1] + ls[2] + ls[3];
    q = lq[0] + lq[1] + lq[2] + lq[3];
    float mean = s * (1.0f / CDIM);
    float var = fmaxf(q * (1.0f / CDIM) - mean * mean, 0.0f);
    float rstd = rsqrtf(var + 1e-5f);
    _Float16* orow = out + (size_t)row * CDIM;
    orow[t]       = (_Float16)((v0 - mean) * rstd * g[t]       + bta[t]);
    orow[t + 256] = (_Float16)((v1 - mean) * rstd * g[t + 256] + bta[t + 256]);
    orow[t + 512] = (_Float16)((v2 - mean) * rstd * g[t + 512] + bta[t + 512]);
}

// ---------------- fp16 MFMA GEMM (m97 structure) ----------------
template <int EPI, typename OutT>  // EPI 0: bias, 1: bias+res, 2: bias+gelu
__global__ __launch_bounds__(256) void hgemm(const _Float16* __restrict__ A,
                                             const _Float16* __restrict__ W,
                                             const float* __restrict__ bias,
                                             const float* __restrict__ res,
                                             OutT* __restrict__ out,
                                             int M, int N, int K) {
    __shared__ _Float16 As[128 * 32];
    __shared__ _Float16 Bs[128 * 32];
    const int t = threadIdx.x;
    const int wid = t >> 6;
    const int l = t & 63;
    const int fr = l & 15;
    const int fq = l >> 4;
    const int wr = wid >> 1, wc = wid & 1;
    const int row0 = blockIdx.y * 128, col0 = blockIdx.x * 128;

    const _Float16* ga = A + (size_t)row0 * K;
    const _Float16* gb = W + (size_t)col0 * K;

    f32x4 acc[4][4] = {};
    const int r_st = t >> 2, c_st = (t & 3) * 8;

    for (int k0 = 0; k0 < K; k0 += 32) {
        __syncthreads();
#pragma unroll
        for (int p = 0; p < 2; ++p) {
            char* la = (char*)As + wid * 1024 + p * 4096;
            char* lb = (char*)Bs + wid * 1024 + p * 4096;
            int r = r_st + p * 64;
            async_copy16(la, ga + (size_t)r * K + k0 + c_st);
            async_copy16(lb, gb + (size_t)r * K + k0 + c_st);
        }
        __syncthreads();

        f16x8 af[4], bf[4];
#pragma unroll
        for (int m = 0; m < 4; ++m)
            af[m] = *reinterpret_cast<const f16x8*>(&As[(wr * 64 + m * 16 + fr) * 32 + fq * 8]);
#pragma unroll
        for (int n = 0; n < 4; ++n)
            bf[n] = *reinterpret_cast<const f16x8*>(&Bs[(wc * 64 + n * 16 + fr) * 32 + fq * 8]);
#pragma unroll
        for (int m = 0; m < 4; ++m)
#pragma unroll
            for (int n = 0; n < 4; ++n)
                acc[m][n] = __builtin_amdgcn_mfma_f32_16x16x32_f16(af[m], bf[n], acc[m][n], 0, 0, 0);
    }

#pragma unroll
    for (int m = 0; m < 4; ++m) {
#pragma unroll
        for (int j = 0; j < 4; ++j) {
            int r = row0 + wr * 64 + m * 16 + fq * 4 + j;
#pragma unroll
            for (int n = 0; n < 4; ++n) {
                int c = col0 + wc * 64 + n * 16 + fr;
                float v = acc[m][n][j] + bias[c];
                if (EPI == 1) v += res[(size_t)r * N + c];
                if (EPI == 2) {
                    float u = v;
                    float inner = 0.7978845608028654f * (u + 0.044715f * u * u * u);
                    v = 0.5f * u * (1.0f + tanhf(inner));
                }
                out[(size_t)r * N + c] = (OutT)v;
            }
        }
    }
}

// ---------------- Flash attention, fp16 MFMA ----------------
// Grid (8, B*H). Block 256 = 4 waves x 16 q-rows = 64 q-rows per q-tile.
// Work-balanced: block bx does q-tiles bx and 15-bx (17 KV-tiles each).
// QK^T: A=Q-frags (reg), B=K rows (LDS [64][104]).
// PV:   A=P (per-wave LDS [16][72] slice), B=V^T (LDS [96][72]).
__global__ __launch_bounds__(256) void attn_kernel(const _Float16* __restrict__ qkv,
                                                   _Float16* __restrict__ y) {
    const int bx = blockIdx.x;  // 0..7
    const int bh = blockIdx.y;
    const int b = bh >> 3, h = bh & 7;
    const int t = threadIdx.x;
    const int wid = t >> 6, l = t & 63;
    const int fr = l & 15, fq = l >> 4;

    __shared__ _Float16 Ks[64 * 104];
    __shared__ _Float16 Vt[96 * 72];
    __shared__ _Float16 Ps[64 * 72];

    const size_t base = (size_t)b * TSEQ * 2304 + h * 96;
    const float scale = 0.10206207261596577f;  // 1/sqrt(96)

    // staging geometry (per thread, constant across tiles)
    const int kkey = t >> 2, kc = t & 3;   // K: key, d-chunk
    const int vkey = l, vrow = wid;        // V: key, d-row-chunk base

    for (int ph = 0; ph < 2; ++ph) {
        const int qt = ph ? (15 - bx) : bx;
        const int q0 = qt * 64;
        const int qrow_g = q0 + wid * 16 + fr;

        // Q A-frags: row = l&15 (+wave), k-slice = (l>>4)*8 (+32s)
        f16x8 qa[3];
#pragma unroll
        for (int s = 0; s < 3; ++s)
            qa[s] = *reinterpret_cast<const f16x8*>(
                &qkv[base + (size_t)qrow_g * 2304 + s * 32 + fq * 8]);

        f32x4 O[6] = {};        // O[n][jj]: row q = wid*16+fq*4+jj, col d = n*16+fr
        float m_i[4], l_i[4];
#pragma unroll
        for (int jj = 0; jj < 4; ++jj) { m_i[jj] = -1e30f; l_i[jj] = 0.0f; }

        // prologue: load KV tile 0 into regs
        f16x8 kreg[3], vreg[3];
#pragma unroll
        for (int p = 0; p < 3; ++p) {
            kreg[p] = *reinterpret_cast<const f16x8*>(
                &qkv[base + (size_t)kkey * 2304 + 768 + 8 * (kc + 4 * p)]);
            vreg[p] = *reinterpret_cast<const f16x8*>(
                &qkv[base + (size_t)vkey * 2304 + 1536 + 8 * (vrow + 4 * p)]);
        }

        for (int kt = 0; kt <= qt; ++kt) {
            __syncthreads();  // prev tile's Ks/Vt reads complete
            // stage K row-major
#pragma unroll
            for (int p = 0; p < 3; ++p)
                *reinterpret_cast<f16x8*>(&Ks[kkey * 104 + 8 * (kc + 4 * p)]) = kreg[p];
            // stage V transposed: Vt[d][key], wave-uniform row per write -> conflict-free
#pragma unroll
            for (int p = 0; p < 3; ++p) {
                int dr = 8 * (vrow + 4 * p);
#pragma unroll
                for (int e = 0; e < 8; ++e)
                    Vt[(dr + e) * 72 + vkey] = vreg[p][e];
            }
            __syncthreads();

            // prefetch next KV tile (overlaps with compute below)
            if (kt < qt) {
                const int k0n = (kt + 1) * 64;
#pragma unroll
                for (int p = 0; p < 3; ++p) {
                    kreg[p] = *reinterpret_cast<const f16x8*>(
                        &qkv[base + (size_t)(k0n + kkey) * 2304 + 768 + 8 * (kc + 4 * p)]);
                    vreg[p] = *reinterpret_cast<const f16x8*>(
                        &qkv[base + (size_t)(k0n + vkey) * 2304 + 1536 + 8 * (vrow + 4 * p)]);
                }
            }

            // S = Q K^T  (4 key-frags x 3 d-slices)
            f32x4 S[4];
#pragma unroll
            for (int n = 0; n < 4; ++n) {
                f32x4 acc = {};
#pragma unroll
                for (int s = 0; s < 3; ++s) {
                    f16x8 kf = *reinterpret_cast<const f16x8*>(
                        &Ks[(n * 16 + fr) * 104 + s * 32 + fq * 8]);
                    acc = __builtin_amdgcn_mfma_f32_16x16x32_f16(qa[s], kf, acc, 0, 0, 0);
                }
                S[n] = acc;
            }

            const bool diag = (kt == qt);
            // online softmax (row = wid*16 + fq*4 + jj; 16 cols/frag across lanes fr)
#pragma unroll
            for (int jj = 0; jj < 4; ++jj) {
                float s0 = S[0][jj] * scale, s1 = S[1][jj] * scale;
                float s2 = S[2][jj] * scale, s3 = S[3][jj] * scale;
                if (diag) {
                    int r = wid * 16 + fq * 4 + jj;
                    if (fr > r)      s0 = -1e30f;
                    if (fr + 16 > r) s1 = -1e30f;
                    if (fr + 32 > r) s2 = -1e30f;
                    if (fr + 48 > r) s3 = -1e30f;
                }
                float mx = fmaxf(fmaxf(s0, s1), fmaxf(s2, s3));
#pragma unroll
                for (int off = 8; off; off >>= 1) mx = fmaxf(mx, __shfl_xor(mx, off, 16));
                float mnew = fmaxf(m_i[jj], mx);
                float sf = __expf(m_i[jj] - mnew);
                m_i[jj] = mnew;
                float p0 = __expf(s0 - mnew), p1 = __expf(s1 - mnew);
                float p2 = __expf(s2 - mnew), p3 = __expf(s3 - mnew);
                float rs = p0 + p1 + p2 + p3;
#pragma unroll
                for (int off = 8; off; off >>= 1) rs += __shfl_xor(rs, off, 16);
                l_i[jj] = l_i[jj] * sf + rs;
                const int prow = wid * 16 + fq * 4 + jj;
                Ps[prow * 72 + fr]      = (_Float16)p0;
                Ps[prow * 72 + 16 + fr] = (_Float16)p1;
                Ps[prow * 72 + 32 + fr] = (_Float16)p2;
                Ps[prow * 72 + 48 + fr] = (_Float16)p3;
#pragma unroll
                for (int n = 0; n < 6; ++n) O[n][jj] *= sf;
            }

            // O += P V  (2 k-slices x 6 d-frags); same-wave LDS RAW handled by compiler
#pragma unroll
            for (int ks = 0; ks < 2; ++ks) {
                f16x8 pf = *reinterpret_cast<const f16x8*>(
                    &Ps[(wid * 16 + fr) * 72 + ks * 32 + fq * 8]);
#pragma unroll
                for (int n = 0; n < 6; ++n) {
                    f16x8 vf = *reinterpret_cast<const f16x8*>(
                        &Vt[(n * 16 + fr) * 72 + ks * 32 + fq * 8]);
                    O[n] = __builtin_amdgcn_mfma_f32_16x16x32_f16(pf, vf, O[n], 0, 0, 0);
                }
            }
        }

        // epilogue: y[b, q, h*96 + d] fp16
#pragma unroll
        for (int jj = 0; jj < 4; ++jj) {
            const int q = q0 + wid * 16 + fq * 4 + jj;
            const float invl = 1.0f / l_i[jj];
            _Float16* yr = y + ((size_t)b * TSEQ + q) * CDIM + h * 96;
#pragma unroll
            for (int n = 0; n < 6; ++n)
                yr[n * 16 + fr] = (_Float16)(O[n][jj] * invl);
        }
    }
}

// ---------------- launch ----------------
extern "C" void kernel_launch(void* const* d_in, const int* in_sizes, int n_in,
                              void* d_out, int out_size, void* d_ws, size_t ws_size,
                              hipStream_t stream) {
    const float* x        = (const float*)d_in[0];
    const float* ln1_g    = (const float*)d_in[1];
    const float* ln1_b    = (const float*)d_in[2];
    const float* ln2_g    = (const float*)d_in[3];
    const float* ln2_b    = (const float*)d_in[4];
    const float* W_attn   = (const float*)d_in[5];
    const float* b_attn   = (const float*)d_in[6];
    const float* W_proj   = (const float*)d_in[7];
    const float* b_proj   = (const float*)d_in[8];
    const float* W_fc     = (const float*)d_in[9];
    const float* b_fc     = (const float*)d_in[10];
    const float* W_fcproj = (const float*)d_in[11];
    const float* b_fcproj = (const float*)d_in[12];
    float* out = (float*)d_out;

    _Float16* qkvh  = (_Float16*)d_ws;                       // M*2304
    _Float16* actsh = qkvh + (size_t)MROWS * 2304;           // M*768
    _Float16* hh    = actsh + (size_t)MROWS * CDIM;          // M*3072
    _Float16* wah   = hh + (size_t)MROWS * 3072;             // 2304*768
    _Float16* wph   = wah + (size_t)2304 * 768;              // 768*768
    _Float16* wfh   = wph + (size_t)768 * 768;               // 3072*768
    _Float16* wfph  = wfh + (size_t)3072 * 768;              // 768*3072

    dim3 blk(256);

    f2h_kernel<<<dim3((2304 * 768 / 4 + 255) / 256), blk, 0, stream>>>(W_attn, wah, 2304 * 768 / 4);
    f2h_kernel<<<dim3((768 * 768 / 4 + 255) / 256), blk, 0, stream>>>(W_proj, wph, 768 * 768 / 4);
    f2h_kernel<<<dim3((3072 * 768 / 4 + 255) / 256), blk, 0, stream>>>(W_fc, wfh, 3072 * 768 / 4);
    f2h_kernel<<<dim3((768 * 3072 / 4 + 255) / 256), blk, 0, stream>>>(W_fcproj, wfph, 768 * 3072 / 4);

    ln_kernel<<<dim3(MROWS), blk, 0, stream>>>(x, ln1_g, ln1_b, actsh);
    hgemm<0, _Float16><<<dim3(2304 / 128, MROWS / 128), blk, 0, stream>>>(
        actsh, wah, b_attn, nullptr, qkvh, MROWS, 2304, CDIM);
    attn_kernel<<<dim3(8, 64), blk, 0, stream>>>(qkvh, actsh);
    hgemm<1, float><<<dim3(CDIM / 128, MROWS / 128), blk, 0, stream>>>(
        actsh, wph, b_proj, x, out, MROWS, CDIM, CDIM);
    ln_kernel<<<dim3(MROWS), blk, 0, stream>>>(out, ln2_g, ln2_b, actsh);
    hgemm<2, _Float16><<<dim3(3072 / 128, MROWS / 128), blk, 0, stream>>>(
        actsh, wfh, b_fc, nullptr, hh, MROWS, 3072, CDIM);
    hgemm<1, float><<<dim3(CDIM / 128, MROWS / 128), blk, 0, stream>>>(
        hh, wfph, b_fcproj, out, out, MROWS, CDIM, 3072);
}